// Round 1
// baseline (562.693 us; speedup 1.0000x reference)
//
#include <hip/hip_runtime.h>
#include <math.h>

#define NP 50000
#define HIDDEN 256
#define NE 800000

// workspace layout (bytes), all float4-aligned where needed
#define OFF_BUF0   0ULL           // h, later A2H  [P,256] f32
#define OFF_BUF1   51200000ULL    // AH            [P,256] f32
#define OFF_WT     102400000ULL   // Wt [512][256] f32 (W1^T ; W2^T)
#define OFF_CNT    102924288ULL   // per-row edge count [P] int
#define OFF_RSTART 103124480ULL   // exclusive scan     [P] int
#define OFF_CURSOR 103324672ULL   // scatter cursor     [P] int
#define OFF_BLK    103524864ULL   // scan block sums    [64] int
#define OFF_COLS   103525120ULL   // sorted edge cols   [E] int
#define OFF_VALS   106725120ULL   // sorted edge vals   [E] f32

// ---------------- embed: h = relu(x @ W_in^T + b_in) ----------------
__global__ void embed_kernel(const float* __restrict__ beta,
                             const float* __restrict__ degree,
                             const float* __restrict__ W_in,
                             const float* __restrict__ b_in,
                             float* __restrict__ h) {
    int p = blockIdx.x;
    int j = threadIdx.x;
    float b = beta[p];
    float d = degree[p];
    float w0 = W_in[j * 3 + 0];
    float w1 = W_in[j * 3 + 1];
    float w2 = W_in[j * 3 + 2];
    float v = fmaf(b, w0, fmaf(b * b, w1, fmaf(d, w2, b_in[j])));
    h[p * HIDDEN + j] = fmaxf(v, 0.0f);
}

// ---------------- transpose W1,W2 -> Wt[512][256] ----------------
__global__ void wt_kernel(const float* __restrict__ W1,
                          const float* __restrict__ W2,
                          float* __restrict__ Wt) {
    int t = blockIdx.x * 256 + threadIdx.x;   // 512*256 threads
    int k = t >> 8;
    int j = t & 255;
    float v = (k < 256) ? W1[j * 256 + k] : W2[j * 256 + (k - 256)];
    Wt[t] = v;
}

// ---------------- CSR build ----------------
__global__ void hist_kernel(const int* __restrict__ rows, int* __restrict__ cnt) {
    int e = blockIdx.x * 256 + threadIdx.x;
    if (e < NE) atomicAdd(&cnt[rows[e]], 1);
}

#define SCAN_T 1024
__global__ void scan1_kernel(const int* __restrict__ cnt,
                             int* __restrict__ row_start,
                             int* __restrict__ blk_sums) {
    __shared__ int s[SCAN_T];
    int tid = threadIdx.x;
    int i = blockIdx.x * SCAN_T + tid;
    int v = (i < NP) ? cnt[i] : 0;
    s[tid] = v;
    __syncthreads();
    for (int off = 1; off < SCAN_T; off <<= 1) {
        int t = (tid >= off) ? s[tid - off] : 0;
        __syncthreads();
        s[tid] += t;
        __syncthreads();
    }
    if (i < NP) row_start[i] = s[tid] - v;          // exclusive
    if (tid == SCAN_T - 1) blk_sums[blockIdx.x] = s[tid];
}

__global__ void scan2_kernel(int* __restrict__ blk_sums, int nblk) {
    int lane = threadIdx.x;                          // 64 threads, 1 wave
    int v = (lane < nblk) ? blk_sums[lane] : 0;
    int x = v;
    for (int off = 1; off < 64; off <<= 1) {
        int t = __shfl_up(x, off);
        if (lane >= off) x += t;
    }
    if (lane < nblk) blk_sums[lane] = x - v;         // exclusive
}

__global__ void scan3_kernel(int* __restrict__ row_start,
                             int* __restrict__ cursor,
                             const int* __restrict__ blk_sums) {
    int i = blockIdx.x * SCAN_T + threadIdx.x;
    if (i < NP) {
        int rs = row_start[i] + blk_sums[i >> 10];
        row_start[i] = rs;
        cursor[i] = rs;
    }
}

__global__ void scatter_kernel(const int* __restrict__ rows,
                               const int* __restrict__ cols,
                               const float* __restrict__ vals,
                               int* __restrict__ cursor,
                               int* __restrict__ cols_s,
                               float* __restrict__ vals_s) {
    int e = blockIdx.x * 256 + threadIdx.x;
    if (e < NE) {
        int r = rows[e];
        int pos = atomicAdd(&cursor[r], 1);
        cols_s[pos] = cols[e];
        vals_s[pos] = vals[e];
    }
}

// ---------------- SpMM: Y[r] = sum_e vals[e] * X[cols[e]] ----------------
__global__ __launch_bounds__(256) void spmm_kernel(
        const int* __restrict__ row_start, const int* __restrict__ cnt,
        const int* __restrict__ cols_s, const float* __restrict__ vals_s,
        const float* __restrict__ X, float* __restrict__ Y) {
    int w = threadIdx.x >> 6;
    int lane = threadIdx.x & 63;
    int r = blockIdx.x * 4 + w;
    if (r >= NP) return;
    int s = row_start[r];
    int n = cnt[r];
    float4 acc = {0.f, 0.f, 0.f, 0.f};
    for (int e = s; e < s + n; ++e) {
        int c = cols_s[e];
        float v = vals_s[e];
        float4 xv = *reinterpret_cast<const float4*>(X + (size_t)c * HIDDEN + lane * 4);
        acc.x = fmaf(v, xv.x, acc.x);
        acc.y = fmaf(v, xv.y, acc.y);
        acc.z = fmaf(v, xv.z, acc.z);
        acc.w = fmaf(v, xv.w, acc.w);
    }
    *reinterpret_cast<float4*>(Y + (size_t)r * HIDDEN + lane * 4) = acc;
}

// ---------------- fused MP GEMM + relu + out-proj + softplus ----------------
#define BM 32
#define BK 32
__global__ __launch_bounds__(256) void mp_out_kernel(
        const float* __restrict__ AH, const float* __restrict__ A2H,
        const float* __restrict__ Wt,
        const float* __restrict__ W_out, const float* __restrict__ b_out,
        float* __restrict__ g) {
    __shared__ float Asub[BM][BK];       // 4 KB
    __shared__ float Bsub[BK][HIDDEN];   // 32 KB
    int tid = threadIdx.x;
    int ty = tid >> 5;    // 0..7  -> rows ty*4 .. ty*4+3
    int tx = tid & 31;    // 0..31 -> cols tx*8 .. tx*8+7
    int p0 = blockIdx.x * BM;

    float acc[4][8];
    #pragma unroll
    for (int i = 0; i < 4; ++i)
        #pragma unroll
        for (int c = 0; c < 8; ++c) acc[i][c] = 0.0f;

    for (int kt = 0; kt < 16; ++kt) {
        const float* Xsrc = (kt < 8) ? AH : A2H;
        int k0 = ((kt < 8) ? kt : kt - 8) * BK;
        // stage A: 32x32 = 256 float4, one per thread
        {
            int r = tid >> 3;
            int kq = tid & 7;
            int gp = p0 + r;
            float4 av = {0.f, 0.f, 0.f, 0.f};
            if (gp < NP)
                av = *reinterpret_cast<const float4*>(Xsrc + (size_t)gp * HIDDEN + k0 + kq * 4);
            *reinterpret_cast<float4*>(&Asub[r][kq * 4]) = av;
        }
        // stage B: 32x256 contiguous from Wt
        {
            const float* Bsrc = Wt + (size_t)(kt * BK) * HIDDEN;
            float* Bflat = &Bsub[0][0];
            #pragma unroll
            for (int it = 0; it < 8; ++it) {
                int q = it * 256 + tid;
                *reinterpret_cast<float4*>(Bflat + q * 4) =
                    *reinterpret_cast<const float4*>(Bsrc + q * 4);
            }
        }
        __syncthreads();
        #pragma unroll
        for (int k = 0; k < BK; ++k) {
            float a0 = Asub[ty * 4 + 0][k];
            float a1 = Asub[ty * 4 + 1][k];
            float a2 = Asub[ty * 4 + 2][k];
            float a3 = Asub[ty * 4 + 3][k];
            float4 bA = *reinterpret_cast<const float4*>(&Bsub[k][tx * 8]);
            float4 bB = *reinterpret_cast<const float4*>(&Bsub[k][tx * 8 + 4]);
            float bv[8] = {bA.x, bA.y, bA.z, bA.w, bB.x, bB.y, bB.z, bB.w};
            #pragma unroll
            for (int c = 0; c < 8; ++c) {
                acc[0][c] = fmaf(a0, bv[c], acc[0][c]);
                acc[1][c] = fmaf(a1, bv[c], acc[1][c]);
                acc[2][c] = fmaf(a2, bv[c], acc[2][c]);
                acc[3][c] = fmaf(a3, bv[c], acc[3][c]);
            }
        }
        __syncthreads();
    }

    // epilogue: relu -> dot W_out -> softplus
    float wout[8];
    #pragma unroll
    for (int c = 0; c < 8; ++c) wout[c] = W_out[tx * 8 + c];
    float bo = b_out[0];
    #pragma unroll
    for (int i = 0; i < 4; ++i) {
        float ps = 0.0f;
        #pragma unroll
        for (int c = 0; c < 8; ++c) {
            float hv = fmaxf(acc[i][c], 0.0f);
            ps = fmaf(hv, wout[c], ps);
        }
        #pragma unroll
        for (int m = 1; m < 32; m <<= 1) ps += __shfl_xor(ps, m);
        if (tx == 0) {
            int p = p0 + ty * 4 + i;
            if (p < NP) {
                float z = ps + bo;
                g[p] = fmaxf(z, 0.0f) + log1pf(expf(-fabsf(z)));
            }
        }
    }
}

extern "C" void kernel_launch(void* const* d_in, const int* in_sizes, int n_in,
                              void* d_out, int out_size, void* d_ws, size_t ws_size,
                              hipStream_t stream) {
    const float* beta   = (const float*)d_in[0];
    const float* degree = (const float*)d_in[1];
    const int*   A_rows = (const int*)d_in[2];
    const int*   A_cols = (const int*)d_in[3];
    const float* A_vals = (const float*)d_in[4];
    const float* W_in   = (const float*)d_in[5];
    const float* b_in   = (const float*)d_in[6];
    const float* W_mp1  = (const float*)d_in[7];
    const float* W_mp2  = (const float*)d_in[8];
    const float* W_out  = (const float*)d_in[9];
    const float* b_out  = (const float*)d_in[10];
    float* g = (float*)d_out;

    char* ws = (char*)d_ws;
    float* buf0     = (float*)(ws + OFF_BUF0);   // h, later A2H
    float* buf1     = (float*)(ws + OFF_BUF1);   // AH
    float* Wt       = (float*)(ws + OFF_WT);
    int*   cnt      = (int*)(ws + OFF_CNT);
    int*   rstart   = (int*)(ws + OFF_RSTART);
    int*   cursor   = (int*)(ws + OFF_CURSOR);
    int*   blk      = (int*)(ws + OFF_BLK);
    int*   cols_s   = (int*)(ws + OFF_COLS);
    float* vals_s   = (float*)(ws + OFF_VALS);

    // zero row counts
    hipMemsetAsync(cnt, 0, NP * sizeof(int), stream);

    // h = relu(x @ W_in^T + b_in)
    embed_kernel<<<NP, 256, 0, stream>>>(beta, degree, W_in, b_in, buf0);

    // Wt = [W1^T ; W2^T]
    wt_kernel<<<512, 256, 0, stream>>>(W_mp1, W_mp2, Wt);

    // CSR build
    hist_kernel<<<(NE + 255) / 256, 256, 0, stream>>>(A_rows, cnt);
    int nblk = (NP + SCAN_T - 1) / SCAN_T;   // 49
    scan1_kernel<<<nblk, SCAN_T, 0, stream>>>(cnt, rstart, blk);
    scan2_kernel<<<1, 64, 0, stream>>>(blk, nblk);
    scan3_kernel<<<nblk, SCAN_T, 0, stream>>>(rstart, cursor, blk);
    scatter_kernel<<<(NE + 255) / 256, 256, 0, stream>>>(A_rows, A_cols, A_vals,
                                                         cursor, cols_s, vals_s);

    // AH = A @ h ; A2H = A @ AH (reuse h buffer)
    spmm_kernel<<<(NP + 3) / 4, 256, 0, stream>>>(rstart, cnt, cols_s, vals_s, buf0, buf1);
    spmm_kernel<<<(NP + 3) / 4, 256, 0, stream>>>(rstart, cnt, cols_s, vals_s, buf1, buf0);

    // g = softplus(relu(AH@W1^T + A2H@W2^T) @ W_out^T + b_out)
    mp_out_kernel<<<(NP + BM - 1) / BM, 256, 0, stream>>>(buf1, buf0, Wt, W_out, b_out, g);
}

// Round 2
// 333.322 us; speedup vs baseline: 1.6881x; 1.6881x over previous
//
#include <hip/hip_runtime.h>
#include <math.h>

#define NP 50000
#define HIDDEN 256
#define NE 800000

// workspace layout (bytes)
#define OFF_X2     0ULL           // [P][512] bf16 : cols 0-255 = AH, 256-511 = A2H
#define OFF_H      51200000ULL    // [P][256] bf16 : embed output
#define OFF_BP     76800000ULL    // Bp [64][256][8] bf16 packed weights
#define OFF_CNT    77062144ULL    // per-row edge count [P] int
#define OFF_RSTART 77262144ULL    // exclusive scan     [P] int
#define OFF_CURSOR 77462144ULL    // scatter cursor     [P] int
#define OFF_BLK    77662144ULL    // scan block sums    [64] int
#define OFF_COLS   77662400ULL    // sorted edge cols   [E] int
#define OFF_VALS   80862400ULL    // sorted edge vals   [E] f32

typedef __attribute__((ext_vector_type(8))) short bf16x8;
typedef __attribute__((ext_vector_type(4))) float f32x4;

__device__ inline unsigned short f2bf(float f) {
    union { float f; unsigned int u; } x; x.f = f;
    unsigned int r = x.u + 0x7FFFu + ((x.u >> 16) & 1u);   // RNE
    return (unsigned short)(r >> 16);
}
__device__ inline float bf2f(unsigned short u) {
    union { unsigned int u; float f; } x; x.u = ((unsigned int)u) << 16; return x.f;
}

// ---------------- embed: h = relu(x @ W_in^T + b_in), bf16 out ----------------
__global__ void embed_kernel(const float* __restrict__ beta,
                             const float* __restrict__ degree,
                             const float* __restrict__ W_in,
                             const float* __restrict__ b_in,
                             unsigned short* __restrict__ h) {
    int t = threadIdx.x;
    int p = blockIdx.x * 2 + (t >> 7);
    int j = (t & 127) * 2;
    float b = beta[p];
    float d = degree[p];
    float b2 = b * b;
    float v0 = fmaf(b, W_in[j*3+0], fmaf(b2, W_in[j*3+1], fmaf(d, W_in[j*3+2], b_in[j])));
    float v1 = fmaf(b, W_in[j*3+3], fmaf(b2, W_in[j*3+4], fmaf(d, W_in[j*3+5], b_in[j+1])));
    ushort2 o;
    o.x = f2bf(fmaxf(v0, 0.0f));
    o.y = f2bf(fmaxf(v1, 0.0f));
    *reinterpret_cast<ushort2*>(&h[p * HIDDEN + j]) = o;
}

// ---------------- pack weights: Bp[k>>3][col][k&7] = Wcat[col][k], bf16 ----------------
__global__ void bp_kernel(const float* __restrict__ W1,
                          const float* __restrict__ W2,
                          unsigned short* __restrict__ Bp) {
    int t = blockIdx.x * 256 + threadIdx.x;   // 512*256
    int j = t >> 9;
    int k = t & 511;
    float v = (k < 256) ? W1[j * 256 + k] : W2[j * 256 + (k - 256)];
    Bp[(k >> 3) * 2048 + j * 8 + (k & 7)] = f2bf(v);
}

// ---------------- CSR build ----------------
__global__ void hist_kernel(const int* __restrict__ rows, int* __restrict__ cnt) {
    int e = blockIdx.x * 256 + threadIdx.x;
    if (e < NE) atomicAdd(&cnt[rows[e]], 1);
}

#define SCAN_T 1024
__global__ void scan1_kernel(const int* __restrict__ cnt,
                             int* __restrict__ row_start,
                             int* __restrict__ blk_sums) {
    __shared__ int s[SCAN_T];
    int tid = threadIdx.x;
    int i = blockIdx.x * SCAN_T + tid;
    int v = (i < NP) ? cnt[i] : 0;
    s[tid] = v;
    __syncthreads();
    for (int off = 1; off < SCAN_T; off <<= 1) {
        int t = (tid >= off) ? s[tid - off] : 0;
        __syncthreads();
        s[tid] += t;
        __syncthreads();
    }
    if (i < NP) row_start[i] = s[tid] - v;
    if (tid == SCAN_T - 1) blk_sums[blockIdx.x] = s[tid];
}

__global__ void scan2_kernel(int* __restrict__ blk_sums, int nblk) {
    int lane = threadIdx.x;
    int v = (lane < nblk) ? blk_sums[lane] : 0;
    int x = v;
    for (int off = 1; off < 64; off <<= 1) {
        int t = __shfl_up(x, off);
        if (lane >= off) x += t;
    }
    if (lane < nblk) blk_sums[lane] = x - v;
}

__global__ void scan3_kernel(int* __restrict__ row_start,
                             int* __restrict__ cursor,
                             const int* __restrict__ blk_sums) {
    int i = blockIdx.x * SCAN_T + threadIdx.x;
    if (i < NP) {
        int rs = row_start[i] + blk_sums[i >> 10];
        row_start[i] = rs;
        cursor[i] = rs;
    }
}

__global__ void scatter_kernel(const int* __restrict__ rows,
                               const int* __restrict__ cols,
                               const float* __restrict__ vals,
                               int* __restrict__ cursor,
                               int* __restrict__ cols_s,
                               float* __restrict__ vals_s) {
    int e = blockIdx.x * 256 + threadIdx.x;
    if (e < NE) {
        int r = rows[e];
        int pos = atomicAdd(&cursor[r], 1);
        cols_s[pos] = cols[e];
        vals_s[pos] = vals[e];
    }
}

// ---------------- SpMM (bf16 in/out, f32 accum): Y[r][c] = sum vals * X[col][c] ----------------
__global__ __launch_bounds__(256) void spmm_kernel(
        const int* __restrict__ row_start, const int* __restrict__ cnt,
        const int* __restrict__ cols_s, const float* __restrict__ vals_s,
        const unsigned short* __restrict__ X, int xstride,
        unsigned short* __restrict__ Y, int ystride) {
    int w = threadIdx.x >> 6;
    int lane = threadIdx.x & 63;
    int r = blockIdx.x * 4 + w;
    if (r >= NP) return;
    int s = row_start[r];
    int n = cnt[r];
    int co = lane * 4;
    float a0 = 0.f, a1 = 0.f, a2 = 0.f, a3 = 0.f;
    for (int e = s; e < s + n; ++e) {
        int c = cols_s[e];
        float v = vals_s[e];
        ushort4 xv = *reinterpret_cast<const ushort4*>(X + (size_t)c * xstride + co);
        a0 = fmaf(v, bf2f(xv.x), a0);
        a1 = fmaf(v, bf2f(xv.y), a1);
        a2 = fmaf(v, bf2f(xv.z), a2);
        a3 = fmaf(v, bf2f(xv.w), a3);
    }
    ushort4 o;
    o.x = f2bf(a0); o.y = f2bf(a1); o.z = f2bf(a2); o.w = f2bf(a3);
    *reinterpret_cast<ushort4*>(Y + (size_t)r * ystride + co) = o;
}

// ---------------- fused MP GEMM (MFMA bf16) + relu + out-proj + softplus ----------------
// block: 512 threads = 8 waves; tile 128 rows x 256 cols; K = 512 in 8 chunks of 64
// wave (wr,wc): wr = w>>2 rows wr*64..+63 ; wc = w&3 cols wc*64..+63
__global__ __launch_bounds__(512, 4) void mp_out_kernel(
        const unsigned short* __restrict__ X2,
        const unsigned short* __restrict__ Bp,
        const float* __restrict__ W_out, const float* __restrict__ b_out,
        float* __restrict__ g) {
    __shared__ unsigned short As[128 * 64];    // 16 KB, XOR-swizzled
    __shared__ unsigned short Bs[8 * 256 * 8]; // 32 KB, [kbl][col][8]
    __shared__ float Ps[4][128];               // 2 KB partials

    int tid = threadIdx.x;
    int w = tid >> 6;
    int lane = tid & 63;
    int wr = w >> 2;
    int wc = w & 3;
    int p0 = blockIdx.x * 128;

    f32x4 acc[4][4];
    #pragma unroll
    for (int i = 0; i < 4; ++i)
        #pragma unroll
        for (int j = 0; j < 4; ++j)
            acc[i][j] = (f32x4){0.f, 0.f, 0.f, 0.f};

    for (int kc = 0; kc < 8; ++kc) {
        __syncthreads();
        // stage A: 1024 x 16B slots. LDS[slot] = A_global[slot ^ swz(row)] (both-sides swizzle)
        #pragma unroll
        for (int it = 0; it < 2; ++it) {
            int slot = it * 512 + tid;
            int ss = slot ^ ((slot >> 3) & 7);         // involution, row bits untouched
            int row = ss >> 3;
            int ko = (ss & 7) * 8;
            int grow = p0 + row;
            if (grow >= NP) grow = NP - 1;
            float4 v = *reinterpret_cast<const float4*>(X2 + (size_t)grow * 512 + kc * 64 + ko);
            *reinterpret_cast<float4*>(&As[slot * 8]) = v;
        }
        // stage B: 2048 x 16B chunks, linear
        #pragma unroll
        for (int it = 0; it < 4; ++it) {
            int c2 = it * 512 + tid;
            float4 v = *reinterpret_cast<const float4*>(
                Bp + ((size_t)(kc * 8 + (c2 >> 8))) * 2048 + (c2 & 255) * 8);
            *reinterpret_cast<float4*>(&Bs[c2 * 8]) = v;
        }
        __syncthreads();
        #pragma unroll
        for (int ks = 0; ks < 2; ++ks) {
            bf16x8 af[4], bfr[4];
            #pragma unroll
            for (int rt = 0; rt < 4; ++rt) {
                int row = wr * 64 + rt * 16 + (lane & 15);
                int elem = row * 64 + ks * 32 + (lane >> 4) * 8;
                elem ^= (row & 7) << 3;                // matches staging swizzle
                af[rt] = *reinterpret_cast<const bf16x8*>(&As[elem]);
            }
            #pragma unroll
            for (int nt = 0; nt < 4; ++nt) {
                int col = wc * 64 + nt * 16 + (lane & 15);
                int kbl = ks * 4 + (lane >> 4);
                bfr[nt] = *reinterpret_cast<const bf16x8*>(&Bs[kbl * 2048 + col * 8]);
            }
            #pragma unroll
            for (int rt = 0; rt < 4; ++rt)
                #pragma unroll
                for (int nt = 0; nt < 4; ++nt)
                    acc[rt][nt] = __builtin_amdgcn_mfma_f32_16x16x32_bf16(
                        af[rt], bfr[nt], acc[rt][nt], 0, 0, 0);
        }
    }

    // epilogue: relu -> dot W_out (this wave's 64 cols) -> LDS partial
    float wv[4];
    #pragma unroll
    for (int nt = 0; nt < 4; ++nt)
        wv[nt] = W_out[wc * 64 + nt * 16 + (lane & 15)];

    float ps[4][4];
    #pragma unroll
    for (int rt = 0; rt < 4; ++rt)
        #pragma unroll
        for (int r = 0; r < 4; ++r) {
            float s = 0.f;
            #pragma unroll
            for (int nt = 0; nt < 4; ++nt)
                s = fmaf(fmaxf(acc[rt][nt][r], 0.0f), wv[nt], s);
            ps[rt][r] = s;
        }
    #pragma unroll
    for (int m = 1; m < 16; m <<= 1)
        #pragma unroll
        for (int rt = 0; rt < 4; ++rt)
            #pragma unroll
            for (int r = 0; r < 4; ++r)
                ps[rt][r] += __shfl_xor(ps[rt][r], m);

    if ((lane & 15) == 0) {
        int rb = wr * 64 + (lane >> 4) * 4;
        #pragma unroll
        for (int rt = 0; rt < 4; ++rt)
            #pragma unroll
            for (int r = 0; r < 4; ++r)
                Ps[wc][rb + rt * 16 + r] = ps[rt][r];
    }
    __syncthreads();
    if (tid < 128) {
        int p = p0 + tid;
        if (p < NP) {
            float z = Ps[0][tid] + Ps[1][tid] + Ps[2][tid] + Ps[3][tid] + b_out[0];
            g[p] = fmaxf(z, 0.0f) + log1pf(expf(-fabsf(z)));
        }
    }
}

extern "C" void kernel_launch(void* const* d_in, const int* in_sizes, int n_in,
                              void* d_out, int out_size, void* d_ws, size_t ws_size,
                              hipStream_t stream) {
    const float* beta   = (const float*)d_in[0];
    const float* degree = (const float*)d_in[1];
    const int*   A_rows = (const int*)d_in[2];
    const int*   A_cols = (const int*)d_in[3];
    const float* A_vals = (const float*)d_in[4];
    const float* W_in   = (const float*)d_in[5];
    const float* b_in   = (const float*)d_in[6];
    const float* W_mp1  = (const float*)d_in[7];
    const float* W_mp2  = (const float*)d_in[8];
    const float* W_out  = (const float*)d_in[9];
    const float* b_out  = (const float*)d_in[10];
    float* g = (float*)d_out;

    char* ws = (char*)d_ws;
    unsigned short* X2   = (unsigned short*)(ws + OFF_X2);
    unsigned short* h    = (unsigned short*)(ws + OFF_H);
    unsigned short* Bp   = (unsigned short*)(ws + OFF_BP);
    int*   cnt    = (int*)(ws + OFF_CNT);
    int*   rstart = (int*)(ws + OFF_RSTART);
    int*   cursor = (int*)(ws + OFF_CURSOR);
    int*   blk    = (int*)(ws + OFF_BLK);
    int*   cols_s = (int*)(ws + OFF_COLS);
    float* vals_s = (float*)(ws + OFF_VALS);

    hipMemsetAsync(cnt, 0, NP * sizeof(int), stream);

    embed_kernel<<<NP / 2, 256, 0, stream>>>(beta, degree, W_in, b_in, h);
    bp_kernel<<<512, 256, 0, stream>>>(W_mp1, W_mp2, Bp);

    hist_kernel<<<(NE + 255) / 256, 256, 0, stream>>>(A_rows, cnt);
    int nblk = (NP + SCAN_T - 1) / SCAN_T;   // 49
    scan1_kernel<<<nblk, SCAN_T, 0, stream>>>(cnt, rstart, blk);
    scan2_kernel<<<1, 64, 0, stream>>>(blk, nblk);
    scan3_kernel<<<nblk, SCAN_T, 0, stream>>>(rstart, cursor, blk);
    scatter_kernel<<<(NE + 255) / 256, 256, 0, stream>>>(A_rows, A_cols, A_vals,
                                                         cursor, cols_s, vals_s);

    // AH = A @ h  -> X2[:, 0:256] ;  A2H = A @ AH -> X2[:, 256:512]
    spmm_kernel<<<(NP + 3) / 4, 256, 0, stream>>>(rstart, cnt, cols_s, vals_s,
                                                  h, HIDDEN, X2, 512);
    spmm_kernel<<<(NP + 3) / 4, 256, 0, stream>>>(rstart, cnt, cols_s, vals_s,
                                                  X2, 512, X2 + 256, 512);

    mp_out_kernel<<<(NP + 127) / 128, 512, 0, stream>>>(X2, Bp, W_out, b_out, g);
}

// Round 3
// 230.311 us; speedup vs baseline: 2.4432x; 1.4473x over previous
//
#include <hip/hip_runtime.h>
#include <math.h>

#define NP 50000
#define HIDDEN 256
#define NE 800000

// workspace layout (bytes)
#define OFF_X2     0ULL           // [P][512] bf16 : cols 0-255 = AH, 256-511 = A2H
#define OFF_BP     51200000ULL    // Bp [64][256][8] bf16 packed weights
#define OFF_CNT    51462144ULL    // per-row edge count [P] int
#define OFF_RSTART 51662144ULL    // exclusive scan     [P] int
#define OFF_CURSOR 51862144ULL    // scatter cursor     [P] int
#define OFF_BLK    52062144ULL    // scan block sums    [64] int
#define OFF_EV     52062400ULL    // sorted edges (col, val-bits) [E] int2

typedef __attribute__((ext_vector_type(8))) short bf16x8;
typedef __attribute__((ext_vector_type(8))) unsigned short u16x8;
typedef __attribute__((ext_vector_type(4))) float f32x4;

__device__ inline unsigned short f2bf(float f) {
    union { float f; unsigned int u; } x; x.f = f;
    unsigned int r = x.u + 0x7FFFu + ((x.u >> 16) & 1u);   // RNE
    return (unsigned short)(r >> 16);
}
__device__ inline float bf2f(unsigned short u) {
    union { unsigned int u; float f; } x; x.u = ((unsigned int)u) << 16; return x.f;
}

// ---------------- pack weights: Bp[k>>3][col][k&7] = Wcat[col][k], bf16 ----------------
__global__ void bp_kernel(const float* __restrict__ W1,
                          const float* __restrict__ W2,
                          unsigned short* __restrict__ Bp) {
    int t = blockIdx.x * 256 + threadIdx.x;   // 512*256
    int j = t >> 9;
    int k = t & 511;
    float v = (k < 256) ? W1[j * 256 + k] : W2[j * 256 + (k - 256)];
    Bp[(k >> 3) * 2048 + j * 8 + (k & 7)] = f2bf(v);
}

// ---------------- CSR build ----------------
__global__ void hist_kernel(const int* __restrict__ rows, int* __restrict__ cnt) {
    int e = blockIdx.x * 256 + threadIdx.x;
    if (e < NE) atomicAdd(&cnt[rows[e]], 1);
}

#define SCAN_T 1024
__global__ void scan1_kernel(const int* __restrict__ cnt,
                             int* __restrict__ row_start,
                             int* __restrict__ blk_sums) {
    __shared__ int s[SCAN_T];
    int tid = threadIdx.x;
    int i = blockIdx.x * SCAN_T + tid;
    int v = (i < NP) ? cnt[i] : 0;
    s[tid] = v;
    __syncthreads();
    for (int off = 1; off < SCAN_T; off <<= 1) {
        int t = (tid >= off) ? s[tid - off] : 0;
        __syncthreads();
        s[tid] += t;
        __syncthreads();
    }
    if (i < NP) row_start[i] = s[tid] - v;
    if (tid == SCAN_T - 1) blk_sums[blockIdx.x] = s[tid];
}

__global__ void scan2_kernel(int* __restrict__ blk_sums, int nblk) {
    int lane = threadIdx.x;
    int v = (lane < nblk) ? blk_sums[lane] : 0;
    int x = v;
    for (int off = 1; off < 64; off <<= 1) {
        int t = __shfl_up(x, off);
        if (lane >= off) x += t;
    }
    if (lane < nblk) blk_sums[lane] = x - v;
}

__global__ void scan3_kernel(int* __restrict__ row_start,
                             int* __restrict__ cursor,
                             const int* __restrict__ blk_sums) {
    int i = blockIdx.x * SCAN_T + threadIdx.x;
    if (i < NP) {
        int rs = row_start[i] + blk_sums[i >> 10];
        row_start[i] = rs;
        cursor[i] = rs;
    }
}

__global__ void scatter_kernel(const int* __restrict__ rows,
                               const int* __restrict__ cols,
                               const float* __restrict__ vals,
                               int* __restrict__ cursor,
                               int2* __restrict__ ev) {
    int e = blockIdx.x * 256 + threadIdx.x;
    if (e < NE) {
        int r = rows[e];
        int pos = atomicAdd(&cursor[r], 1);
        ev[pos] = make_int2(cols[e], __float_as_int(vals[e]));
    }
}

// ---------------- hop 1 fused: AH[r] = sum_e val * relu(W_in . x[col] + b_in) ----------------
// wave per row; halves process 2 edges concurrently; h recomputed from beta/degree (8B/edge)
__global__ __launch_bounds__(256) void spmm_embed_kernel(
        const int* __restrict__ row_start, const int* __restrict__ cnt,
        const int2* __restrict__ ev,
        const float* __restrict__ beta, const float* __restrict__ degree,
        const float* __restrict__ W_in, const float* __restrict__ b_in,
        unsigned short* __restrict__ Y, int ystride) {
    int w = threadIdx.x >> 6;
    int lane = threadIdx.x & 63;
    int r = blockIdx.x * 4 + w;
    if (r >= NP) return;
    int half = lane >> 5;
    int fo = (lane & 31) * 8;

    float wr0[8], wr1[8], wr2[8], br[8];
    #pragma unroll
    for (int j = 0; j < 8; ++j) {
        wr0[j] = W_in[(fo + j) * 3 + 0];
        wr1[j] = W_in[(fo + j) * 3 + 1];
        wr2[j] = W_in[(fo + j) * 3 + 2];
        br[j]  = b_in[fo + j];
    }

    int s = row_start[r];
    int n = cnt[r];
    float acc[8] = {0.f,0.f,0.f,0.f,0.f,0.f,0.f,0.f};
    for (int base = 0; base < n; base += 64) {
        int m = min(n - base, 64);
        int col_l = 0; float val_l = 0.f;
        if (lane < m) {
            int2 e2 = ev[s + base + lane];
            col_l = e2.x; val_l = __int_as_float(e2.y);
        }
        for (int i = 0; i < m; i += 2) {
            int e = i + half;
            int es = (e < m) ? e : 0;
            int c = __shfl(col_l, es);
            float v = __shfl(val_l, es);
            if (e >= m) v = 0.f;
            float b = beta[c];
            float d = degree[c];
            float b2 = b * b;
            #pragma unroll
            for (int j = 0; j < 8; ++j) {
                float t = fmaf(b, wr0[j], fmaf(b2, wr1[j], fmaf(d, wr2[j], br[j])));
                acc[j] = fmaf(v, fmaxf(t, 0.f), acc[j]);
            }
        }
    }
    #pragma unroll
    for (int j = 0; j < 8; ++j) acc[j] += __shfl_xor(acc[j], 32);
    if (half == 0) {
        u16x8 o;
        #pragma unroll
        for (int j = 0; j < 8; ++j) o[j] = f2bf(acc[j]);
        *reinterpret_cast<u16x8*>(Y + (size_t)r * ystride + fo) = o;
    }
}

// ---------------- hop 2: gather SpMM, 2 edges/wave concurrent, 16B/lane, 4-deep MLP ----------------
__global__ __launch_bounds__(256) void spmm_gather_kernel(
        const int* __restrict__ row_start, const int* __restrict__ cnt,
        const int2* __restrict__ ev,
        const unsigned short* __restrict__ X, int xstride,
        unsigned short* __restrict__ Y, int ystride) {
    int w = threadIdx.x >> 6;
    int lane = threadIdx.x & 63;
    int r = blockIdx.x * 4 + w;
    if (r >= NP) return;
    int half = lane >> 5;
    int fo = (lane & 31) * 8;

    int s = row_start[r];
    int n = cnt[r];
    float acc[8] = {0.f,0.f,0.f,0.f,0.f,0.f,0.f,0.f};
    for (int base = 0; base < n; base += 64) {
        int m = min(n - base, 64);
        int col_l = 0; float val_l = 0.f;
        if (lane < m) {
            int2 e2 = ev[s + base + lane];
            col_l = e2.x; val_l = __int_as_float(e2.y);
        }
        int i = 0;
        for (; i + 8 <= m; i += 8) {
            int c0 = __shfl(col_l, i + 0 + half);
            int c1 = __shfl(col_l, i + 2 + half);
            int c2 = __shfl(col_l, i + 4 + half);
            int c3 = __shfl(col_l, i + 6 + half);
            float v0 = __shfl(val_l, i + 0 + half);
            float v1 = __shfl(val_l, i + 2 + half);
            float v2 = __shfl(val_l, i + 4 + half);
            float v3 = __shfl(val_l, i + 6 + half);
            u16x8 x0 = *reinterpret_cast<const u16x8*>(X + (size_t)c0 * xstride + fo);
            u16x8 x1 = *reinterpret_cast<const u16x8*>(X + (size_t)c1 * xstride + fo);
            u16x8 x2 = *reinterpret_cast<const u16x8*>(X + (size_t)c2 * xstride + fo);
            u16x8 x3 = *reinterpret_cast<const u16x8*>(X + (size_t)c3 * xstride + fo);
            #pragma unroll
            for (int j = 0; j < 8; ++j) acc[j] = fmaf(v0, bf2f(x0[j]), acc[j]);
            #pragma unroll
            for (int j = 0; j < 8; ++j) acc[j] = fmaf(v1, bf2f(x1[j]), acc[j]);
            #pragma unroll
            for (int j = 0; j < 8; ++j) acc[j] = fmaf(v2, bf2f(x2[j]), acc[j]);
            #pragma unroll
            for (int j = 0; j < 8; ++j) acc[j] = fmaf(v3, bf2f(x3[j]), acc[j]);
        }
        for (; i < m; i += 2) {
            int e = i + half;
            int es = (e < m) ? e : 0;
            int c = __shfl(col_l, es);
            float v = __shfl(val_l, es);
            if (e < m) {
                u16x8 xv = *reinterpret_cast<const u16x8*>(X + (size_t)c * xstride + fo);
                #pragma unroll
                for (int j = 0; j < 8; ++j) acc[j] = fmaf(v, bf2f(xv[j]), acc[j]);
            }
        }
    }
    #pragma unroll
    for (int j = 0; j < 8; ++j) acc[j] += __shfl_xor(acc[j], 32);
    if (half == 0) {
        u16x8 o;
        #pragma unroll
        for (int j = 0; j < 8; ++j) o[j] = f2bf(acc[j]);
        *reinterpret_cast<u16x8*>(Y + (size_t)r * ystride + fo) = o;
    }
}

// ---------------- fused MP GEMM (MFMA bf16) + relu + out-proj + softplus ----------------
// block: 512 threads = 8 waves; tile 128 rows x 256 cols; K = 512 in 8 chunks of 64
__global__ __launch_bounds__(512, 4) void mp_out_kernel(
        const unsigned short* __restrict__ X2,
        const unsigned short* __restrict__ Bp,
        const float* __restrict__ W_out, const float* __restrict__ b_out,
        float* __restrict__ g) {
    __shared__ unsigned short As[128 * 64];    // 16 KB, XOR-swizzled
    __shared__ unsigned short Bs[8 * 256 * 8]; // 32 KB, [kbl][col][8]
    __shared__ float Ps[4][128];               // 2 KB partials

    int tid = threadIdx.x;
    int w = tid >> 6;
    int lane = tid & 63;
    int wr = w >> 2;
    int wc = w & 3;
    int p0 = blockIdx.x * 128;

    f32x4 acc[4][4];
    #pragma unroll
    for (int i = 0; i < 4; ++i)
        #pragma unroll
        for (int j = 0; j < 4; ++j)
            acc[i][j] = (f32x4){0.f, 0.f, 0.f, 0.f};

    for (int kc = 0; kc < 8; ++kc) {
        __syncthreads();
        // stage A: 1024 x 16B slots. LDS[slot] = A_global[slot ^ swz(row)] (both-sides swizzle)
        #pragma unroll
        for (int it = 0; it < 2; ++it) {
            int slot = it * 512 + tid;
            int ss = slot ^ ((slot >> 3) & 7);         // involution, row bits untouched
            int row = ss >> 3;
            int ko = (ss & 7) * 8;
            int grow = p0 + row;
            if (grow >= NP) grow = NP - 1;
            float4 v = *reinterpret_cast<const float4*>(X2 + (size_t)grow * 512 + kc * 64 + ko);
            *reinterpret_cast<float4*>(&As[slot * 8]) = v;
        }
        // stage B: 2048 x 16B chunks, linear
        #pragma unroll
        for (int it = 0; it < 4; ++it) {
            int c2 = it * 512 + tid;
            float4 v = *reinterpret_cast<const float4*>(
                Bp + ((size_t)(kc * 8 + (c2 >> 8))) * 2048 + (c2 & 255) * 8);
            *reinterpret_cast<float4*>(&Bs[c2 * 8]) = v;
        }
        __syncthreads();
        #pragma unroll
        for (int ks = 0; ks < 2; ++ks) {
            bf16x8 af[4], bfr[4];
            #pragma unroll
            for (int rt = 0; rt < 4; ++rt) {
                int row = wr * 64 + rt * 16 + (lane & 15);
                int elem = row * 64 + ks * 32 + (lane >> 4) * 8;
                elem ^= (row & 7) << 3;                // matches staging swizzle
                af[rt] = *reinterpret_cast<const bf16x8*>(&As[elem]);
            }
            #pragma unroll
            for (int nt = 0; nt < 4; ++nt) {
                int col = wc * 64 + nt * 16 + (lane & 15);
                int kbl = ks * 4 + (lane >> 4);
                bfr[nt] = *reinterpret_cast<const bf16x8*>(&Bs[kbl * 2048 + col * 8]);
            }
            #pragma unroll
            for (int rt = 0; rt < 4; ++rt)
                #pragma unroll
                for (int nt = 0; nt < 4; ++nt)
                    acc[rt][nt] = __builtin_amdgcn_mfma_f32_16x16x32_bf16(
                        af[rt], bfr[nt], acc[rt][nt], 0, 0, 0);
        }
    }

    // epilogue: relu -> dot W_out (this wave's 64 cols) -> LDS partial
    float wv[4];
    #pragma unroll
    for (int nt = 0; nt < 4; ++nt)
        wv[nt] = W_out[wc * 64 + nt * 16 + (lane & 15)];

    float ps[4][4];
    #pragma unroll
    for (int rt = 0; rt < 4; ++rt)
        #pragma unroll
        for (int r = 0; r < 4; ++r) {
            float s = 0.f;
            #pragma unroll
            for (int nt = 0; nt < 4; ++nt)
                s = fmaf(fmaxf(acc[rt][nt][r], 0.0f), wv[nt], s);
            ps[rt][r] = s;
        }
    #pragma unroll
    for (int m = 1; m < 16; m <<= 1)
        #pragma unroll
        for (int rt = 0; rt < 4; ++rt)
            #pragma unroll
            for (int r = 0; r < 4; ++r)
                ps[rt][r] += __shfl_xor(ps[rt][r], m);

    if ((lane & 15) == 0) {
        int rb = wr * 64 + (lane >> 4) * 4;
        #pragma unroll
        for (int rt = 0; rt < 4; ++rt)
            #pragma unroll
            for (int r = 0; r < 4; ++r)
                Ps[wc][rb + rt * 16 + r] = ps[rt][r];
    }
    __syncthreads();
    if (tid < 128) {
        int p = p0 + tid;
        if (p < NP) {
            float z = Ps[0][tid] + Ps[1][tid] + Ps[2][tid] + Ps[3][tid] + b_out[0];
            g[p] = fmaxf(z, 0.0f) + log1pf(expf(-fabsf(z)));
        }
    }
}

extern "C" void kernel_launch(void* const* d_in, const int* in_sizes, int n_in,
                              void* d_out, int out_size, void* d_ws, size_t ws_size,
                              hipStream_t stream) {
    const float* beta   = (const float*)d_in[0];
    const float* degree = (const float*)d_in[1];
    const int*   A_rows = (const int*)d_in[2];
    const int*   A_cols = (const int*)d_in[3];
    const float* A_vals = (const float*)d_in[4];
    const float* W_in   = (const float*)d_in[5];
    const float* b_in   = (const float*)d_in[6];
    const float* W_mp1  = (const float*)d_in[7];
    const float* W_mp2  = (const float*)d_in[8];
    const float* W_out  = (const float*)d_in[9];
    const float* b_out  = (const float*)d_in[10];
    float* g = (float*)d_out;

    char* ws = (char*)d_ws;
    unsigned short* X2 = (unsigned short*)(ws + OFF_X2);
    unsigned short* Bp = (unsigned short*)(ws + OFF_BP);
    int*  cnt    = (int*)(ws + OFF_CNT);
    int*  rstart = (int*)(ws + OFF_RSTART);
    int*  cursor = (int*)(ws + OFF_CURSOR);
    int*  blk    = (int*)(ws + OFF_BLK);
    int2* ev     = (int2*)(ws + OFF_EV);

    hipMemsetAsync(cnt, 0, NP * sizeof(int), stream);

    bp_kernel<<<512, 256, 0, stream>>>(W_mp1, W_mp2, Bp);

    hist_kernel<<<(NE + 255) / 256, 256, 0, stream>>>(A_rows, cnt);
    int nblk = (NP + SCAN_T - 1) / SCAN_T;   // 49
    scan1_kernel<<<nblk, SCAN_T, 0, stream>>>(cnt, rstart, blk);
    scan2_kernel<<<1, 64, 0, stream>>>(blk, nblk);
    scan3_kernel<<<nblk, SCAN_T, 0, stream>>>(rstart, cursor, blk);
    scatter_kernel<<<(NE + 255) / 256, 256, 0, stream>>>(A_rows, A_cols, A_vals,
                                                         cursor, ev);

    // AH = A @ relu(x W_in^T + b_in) -> X2[:, 0:256]  (h recomputed per edge)
    spmm_embed_kernel<<<(NP + 3) / 4, 256, 0, stream>>>(rstart, cnt, ev,
                                                        beta, degree, W_in, b_in,
                                                        X2, 512);
    // A2H = A @ AH -> X2[:, 256:512]
    spmm_gather_kernel<<<(NP + 3) / 4, 256, 0, stream>>>(rstart, cnt, ev,
                                                         X2, 512, X2 + 256, 512);

    mp_out_kernel<<<(NP + 127) / 128, 512, 0, stream>>>(X2, Bp, W_out, b_out, g);
}

// Round 4
// 176.157 us; speedup vs baseline: 3.1943x; 1.3074x over previous
//
#include <hip/hip_runtime.h>
#include <math.h>

#define NP 50000
#define HIDDEN 256
#define NE 800000
#define CAP 64          // ELL capacity; P(Poisson(16) > 64) ~ 1e-20

// workspace layout (bytes)
#define OFF_X2     0ULL           // [P][512] bf16 : cols 0-255 = AH, 256-511 = A2H
#define OFF_BP     51200000ULL    // Bp [64][256][8] bf16 packed weights
#define OFF_CNT    51462144ULL    // per-row edge count [P] int
#define OFF_PC     51662144ULL    // packed (beta,degree) [P] float2
#define OFF_EV     52062144ULL    // ELL edges (col, val-bits) [P][CAP] int2

typedef __attribute__((ext_vector_type(8))) short bf16x8;
typedef __attribute__((ext_vector_type(8))) unsigned short u16x8;
typedef __attribute__((ext_vector_type(4))) float f32x4;

__device__ inline unsigned short f2bf(float f) {
    union { float f; unsigned int u; } x; x.f = f;
    unsigned int r = x.u + 0x7FFFu + ((x.u >> 16) & 1u);   // RNE
    return (unsigned short)(r >> 16);
}
__device__ inline float bf2f(unsigned short u) {
    union { unsigned int u; float f; } x; x.u = ((unsigned int)u) << 16; return x.f;
}

// ---------------- pack weights: Bp[k>>3][col][k&7] = Wcat[col][k], bf16 ----------------
__global__ void bp_kernel(const float* __restrict__ W1,
                          const float* __restrict__ W2,
                          unsigned short* __restrict__ Bp) {
    int t = blockIdx.x * 256 + threadIdx.x;   // 512*256
    int j = t >> 9;
    int k = t & 511;
    float v = (k < 256) ? W1[j * 256 + k] : W2[j * 256 + (k - 256)];
    Bp[(k >> 3) * 2048 + j * 8 + (k & 7)] = f2bf(v);
}

// ---------------- pack (beta, degree) ----------------
__global__ void pc_kernel(const float* __restrict__ beta,
                          const float* __restrict__ degree,
                          float2* __restrict__ pc) {
    int i = blockIdx.x * 256 + threadIdx.x;
    if (i < NP) pc[i] = make_float2(beta[i], degree[i]);
}

// ---------------- ELL scatter (cnt must be zeroed) ----------------
__global__ void scatter_ell(const int* __restrict__ rows,
                            const int* __restrict__ cols,
                            const float* __restrict__ vals,
                            int* __restrict__ cnt,
                            int2* __restrict__ ev) {
    int e = blockIdx.x * 256 + threadIdx.x;
    if (e < NE) {
        int r = rows[e];
        int pos = atomicAdd(&cnt[r], 1);
        if (pos < CAP)
            ev[(size_t)r * CAP + pos] = make_int2(cols[e], __float_as_int(vals[e]));
    }
}

// ---------------- hop 1 fused: AH[r] = sum_e val * relu(W_in . x[col] + b_in) ----------------
// wave per row; edges preloaded one per lane; halves process 2 edges concurrently
__global__ __launch_bounds__(256) void spmm_embed_kernel(
        const int* __restrict__ cnt, const int2* __restrict__ ev,
        const float2* __restrict__ pc,
        const float* __restrict__ W_in, const float* __restrict__ b_in,
        unsigned short* __restrict__ Y, int ystride) {
    int w = threadIdx.x >> 6;
    int lane = threadIdx.x & 63;
    int r = blockIdx.x * 4 + w;
    if (r >= NP) return;
    int half = lane >> 5;
    int fo = (lane & 31) * 8;

    int n = min(cnt[r], CAP);
    int2 e2 = make_int2(0, 0);
    if (lane < n) e2 = ev[(size_t)r * CAP + lane];
    int col_l = e2.x;
    float val_l = __int_as_float(e2.y);

    float wr0[8], wr1[8], wr2[8], br[8];
    #pragma unroll
    for (int j = 0; j < 8; ++j) {
        wr0[j] = W_in[(fo + j) * 3 + 0];
        wr1[j] = W_in[(fo + j) * 3 + 1];
        wr2[j] = W_in[(fo + j) * 3 + 2];
        br[j]  = b_in[fo + j];
    }

    float acc[8] = {0.f,0.f,0.f,0.f,0.f,0.f,0.f,0.f};
    for (int i = 0; i < n; i += 8) {
        float2 p[4]; float vv[4];
        #pragma unroll
        for (int k = 0; k < 4; ++k) {
            int e = i + 2 * k + half;
            int es = (e < n) ? e : 0;
            int c = __shfl(col_l, es);
            vv[k] = __shfl(val_l, es);
            if (e >= n) vv[k] = 0.f;
            p[k] = pc[c];
        }
        #pragma unroll
        for (int k = 0; k < 4; ++k) {
            float b = p[k].x, d = p[k].y, v = vv[k];
            float b2 = b * b;
            #pragma unroll
            for (int j = 0; j < 8; ++j) {
                float t = fmaf(b, wr0[j], fmaf(b2, wr1[j], fmaf(d, wr2[j], br[j])));
                acc[j] = fmaf(v, fmaxf(t, 0.f), acc[j]);
            }
        }
    }
    #pragma unroll
    for (int j = 0; j < 8; ++j) acc[j] += __shfl_xor(acc[j], 32);
    if (half == 0) {
        u16x8 o;
        #pragma unroll
        for (int j = 0; j < 8; ++j) o[j] = f2bf(acc[j]);
        *reinterpret_cast<u16x8*>(Y + (size_t)r * ystride + fo) = o;
    }
}

// ---------------- hop 2: gather SpMM, tail-free 4-deep unroll per half ----------------
__global__ __launch_bounds__(256) void spmm_gather_kernel(
        const int* __restrict__ cnt, const int2* __restrict__ ev,
        const unsigned short* __restrict__ X, int xstride,
        unsigned short* __restrict__ Y, int ystride) {
    int w = threadIdx.x >> 6;
    int lane = threadIdx.x & 63;
    int r = blockIdx.x * 4 + w;
    if (r >= NP) return;
    int half = lane >> 5;
    int fo = (lane & 31) * 8;

    int n = min(cnt[r], CAP);
    int2 e2 = make_int2(0, 0);
    if (lane < n) e2 = ev[(size_t)r * CAP + lane];
    int col_l = e2.x;
    float val_l = __int_as_float(e2.y);

    float acc[8] = {0.f,0.f,0.f,0.f,0.f,0.f,0.f,0.f};
    for (int i = 0; i < n; i += 8) {
        int cc[4]; float vv[4];
        #pragma unroll
        for (int k = 0; k < 4; ++k) {
            int e = i + 2 * k + half;
            int es = (e < n) ? e : 0;
            cc[k] = __shfl(col_l, es);
            vv[k] = __shfl(val_l, es);
            if (e >= n) vv[k] = 0.f;
        }
        u16x8 x0 = *reinterpret_cast<const u16x8*>(X + (size_t)cc[0] * xstride + fo);
        u16x8 x1 = *reinterpret_cast<const u16x8*>(X + (size_t)cc[1] * xstride + fo);
        u16x8 x2 = *reinterpret_cast<const u16x8*>(X + (size_t)cc[2] * xstride + fo);
        u16x8 x3 = *reinterpret_cast<const u16x8*>(X + (size_t)cc[3] * xstride + fo);
        #pragma unroll
        for (int j = 0; j < 8; ++j) acc[j] = fmaf(vv[0], bf2f(x0[j]), acc[j]);
        #pragma unroll
        for (int j = 0; j < 8; ++j) acc[j] = fmaf(vv[1], bf2f(x1[j]), acc[j]);
        #pragma unroll
        for (int j = 0; j < 8; ++j) acc[j] = fmaf(vv[2], bf2f(x2[j]), acc[j]);
        #pragma unroll
        for (int j = 0; j < 8; ++j) acc[j] = fmaf(vv[3], bf2f(x3[j]), acc[j]);
    }
    #pragma unroll
    for (int j = 0; j < 8; ++j) acc[j] += __shfl_xor(acc[j], 32);
    if (half == 0) {
        u16x8 o;
        #pragma unroll
        for (int j = 0; j < 8; ++j) o[j] = f2bf(acc[j]);
        *reinterpret_cast<u16x8*>(Y + (size_t)r * ystride + fo) = o;
    }
}

// ---------------- fused MP GEMM (MFMA bf16) + relu + out-proj + softplus ----------------
// block: 512 threads = 8 waves; tile 128 rows x 256 cols; K = 512 in 8 chunks of 64
__global__ __launch_bounds__(512, 4) void mp_out_kernel(
        const unsigned short* __restrict__ X2,
        const unsigned short* __restrict__ Bp,
        const float* __restrict__ W_out, const float* __restrict__ b_out,
        float* __restrict__ g) {
    __shared__ unsigned short As[128 * 64];    // 16 KB, XOR-swizzled
    __shared__ unsigned short Bs[8 * 256 * 8]; // 32 KB, [kbl][col][8]
    __shared__ float Ps[4][128];               // 2 KB partials

    int tid = threadIdx.x;
    int w = tid >> 6;
    int lane = tid & 63;
    int wr = w >> 2;
    int wc = w & 3;
    int p0 = blockIdx.x * 128;

    f32x4 acc[4][4];
    #pragma unroll
    for (int i = 0; i < 4; ++i)
        #pragma unroll
        for (int j = 0; j < 4; ++j)
            acc[i][j] = (f32x4){0.f, 0.f, 0.f, 0.f};

    for (int kc = 0; kc < 8; ++kc) {
        __syncthreads();
        // stage A: 1024 x 16B slots. LDS[slot] = A_global[slot ^ swz(row)] (both-sides swizzle)
        #pragma unroll
        for (int it = 0; it < 2; ++it) {
            int slot = it * 512 + tid;
            int ss = slot ^ ((slot >> 3) & 7);         // involution, row bits untouched
            int row = ss >> 3;
            int ko = (ss & 7) * 8;
            int grow = p0 + row;
            if (grow >= NP) grow = NP - 1;
            float4 v = *reinterpret_cast<const float4*>(X2 + (size_t)grow * 512 + kc * 64 + ko);
            *reinterpret_cast<float4*>(&As[slot * 8]) = v;
        }
        // stage B: 2048 x 16B chunks, linear
        #pragma unroll
        for (int it = 0; it < 4; ++it) {
            int c2 = it * 512 + tid;
            float4 v = *reinterpret_cast<const float4*>(
                Bp + ((size_t)(kc * 8 + (c2 >> 8))) * 2048 + (c2 & 255) * 8);
            *reinterpret_cast<float4*>(&Bs[c2 * 8]) = v;
        }
        __syncthreads();
        #pragma unroll
        for (int ks = 0; ks < 2; ++ks) {
            bf16x8 af[4], bfr[4];
            #pragma unroll
            for (int rt = 0; rt < 4; ++rt) {
                int row = wr * 64 + rt * 16 + (lane & 15);
                int elem = row * 64 + ks * 32 + (lane >> 4) * 8;
                elem ^= (row & 7) << 3;                // matches staging swizzle
                af[rt] = *reinterpret_cast<const bf16x8*>(&As[elem]);
            }
            #pragma unroll
            for (int nt = 0; nt < 4; ++nt) {
                int col = wc * 64 + nt * 16 + (lane & 15);
                int kbl = ks * 4 + (lane >> 4);
                bfr[nt] = *reinterpret_cast<const bf16x8*>(&Bs[kbl * 2048 + col * 8]);
            }
            #pragma unroll
            for (int rt = 0; rt < 4; ++rt)
                #pragma unroll
                for (int nt = 0; nt < 4; ++nt)
                    acc[rt][nt] = __builtin_amdgcn_mfma_f32_16x16x32_bf16(
                        af[rt], bfr[nt], acc[rt][nt], 0, 0, 0);
        }
    }

    // epilogue: relu -> dot W_out (this wave's 64 cols) -> LDS partial
    float wv[4];
    #pragma unroll
    for (int nt = 0; nt < 4; ++nt)
        wv[nt] = W_out[wc * 64 + nt * 16 + (lane & 15)];

    float ps[4][4];
    #pragma unroll
    for (int rt = 0; rt < 4; ++rt)
        #pragma unroll
        for (int r = 0; r < 4; ++r) {
            float s = 0.f;
            #pragma unroll
            for (int nt = 0; nt < 4; ++nt)
                s = fmaf(fmaxf(acc[rt][nt][r], 0.0f), wv[nt], s);
            ps[rt][r] = s;
        }
    #pragma unroll
    for (int m = 1; m < 16; m <<= 1)
        #pragma unroll
        for (int rt = 0; rt < 4; ++rt)
            #pragma unroll
            for (int r = 0; r < 4; ++r)
                ps[rt][r] += __shfl_xor(ps[rt][r], m);

    if ((lane & 15) == 0) {
        int rb = wr * 64 + (lane >> 4) * 4;
        #pragma unroll
        for (int rt = 0; rt < 4; ++rt)
            #pragma unroll
            for (int r = 0; r < 4; ++r)
                Ps[wc][rb + rt * 16 + r] = ps[rt][r];
    }
    __syncthreads();
    if (tid < 128) {
        int p = p0 + tid;
        if (p < NP) {
            float z = Ps[0][tid] + Ps[1][tid] + Ps[2][tid] + Ps[3][tid] + b_out[0];
            g[p] = fmaxf(z, 0.0f) + log1pf(expf(-fabsf(z)));
        }
    }
}

extern "C" void kernel_launch(void* const* d_in, const int* in_sizes, int n_in,
                              void* d_out, int out_size, void* d_ws, size_t ws_size,
                              hipStream_t stream) {
    const float* beta   = (const float*)d_in[0];
    const float* degree = (const float*)d_in[1];
    const int*   A_rows = (const int*)d_in[2];
    const int*   A_cols = (const int*)d_in[3];
    const float* A_vals = (const float*)d_in[4];
    const float* W_in   = (const float*)d_in[5];
    const float* b_in   = (const float*)d_in[6];
    const float* W_mp1  = (const float*)d_in[7];
    const float* W_mp2  = (const float*)d_in[8];
    const float* W_out  = (const float*)d_in[9];
    const float* b_out  = (const float*)d_in[10];
    float* g = (float*)d_out;

    char* ws = (char*)d_ws;
    unsigned short* X2 = (unsigned short*)(ws + OFF_X2);
    unsigned short* Bp = (unsigned short*)(ws + OFF_BP);
    int*    cnt = (int*)(ws + OFF_CNT);
    float2* pc  = (float2*)(ws + OFF_PC);
    int2*   ev  = (int2*)(ws + OFF_EV);

    hipMemsetAsync(cnt, 0, NP * sizeof(int), stream);

    bp_kernel<<<512, 256, 0, stream>>>(W_mp1, W_mp2, Bp);
    pc_kernel<<<(NP + 255) / 256, 256, 0, stream>>>(beta, degree, pc);

    scatter_ell<<<(NE + 255) / 256, 256, 0, stream>>>(A_rows, A_cols, A_vals, cnt, ev);

    // AH = A @ relu(x W_in^T + b_in) -> X2[:, 0:256]  (h recomputed per edge)
    spmm_embed_kernel<<<(NP + 3) / 4, 256, 0, stream>>>(cnt, ev, pc, W_in, b_in,
                                                        X2, 512);
    // A2H = A @ AH -> X2[:, 256:512]
    spmm_gather_kernel<<<(NP + 3) / 4, 256, 0, stream>>>(cnt, ev, X2, 512,
                                                         X2 + 256, 512);

    mp_out_kernel<<<(NP + 127) / 128, 512, 0, stream>>>(X2, Bp, W_out, b_out, g);
}

// Round 5
// 175.197 us; speedup vs baseline: 3.2118x; 1.0055x over previous
//
#include <hip/hip_runtime.h>
#include <math.h>

#define NP 50000
#define HIDDEN 256
#define NE 800000
#define CAP 64          // ELL capacity; P(Poisson(16) > 64) ~ 1e-20

// workspace layout (bytes)
#define OFF_AH     0ULL           // [P][256] bf16 : AH
#define OFF_A2H    25600000ULL    // [P][256] bf16 : A2H
#define OFF_BP     51200000ULL    // Bp [64][256][8] bf16 packed weights
#define OFF_CNT    51462144ULL    // per-row edge count [P] int
#define OFF_PC     51662144ULL    // packed (beta,degree) [P] float2
#define OFF_EV     52062144ULL    // ELL edges (col, val-bits) [P][CAP] int2

typedef __attribute__((ext_vector_type(8))) short bf16x8;
typedef __attribute__((ext_vector_type(8))) unsigned short u16x8;
typedef __attribute__((ext_vector_type(4))) float f32x4;

__device__ inline unsigned short f2bf(float f) {
    union { float f; unsigned int u; } x; x.f = f;
    unsigned int r = x.u + 0x7FFFu + ((x.u >> 16) & 1u);   // RNE
    return (unsigned short)(r >> 16);
}
__device__ inline float bf2f(unsigned short u) {
    union { unsigned int u; float f; } x; x.u = ((unsigned int)u) << 16; return x.f;
}

// ---------------- pack weights: Bp[k>>3][col][k&7] = Wcat[col][k], bf16 ----------------
__global__ void bp_kernel(const float* __restrict__ W1,
                          const float* __restrict__ W2,
                          unsigned short* __restrict__ Bp) {
    int t = blockIdx.x * 256 + threadIdx.x;   // 512*256
    int j = t >> 9;
    int k = t & 511;
    float v = (k < 256) ? W1[j * 256 + k] : W2[j * 256 + (k - 256)];
    Bp[(k >> 3) * 2048 + j * 8 + (k & 7)] = f2bf(v);
}

// ---------------- pack (beta, degree) ----------------
__global__ void pc_kernel(const float* __restrict__ beta,
                          const float* __restrict__ degree,
                          float2* __restrict__ pc) {
    int i = blockIdx.x * 256 + threadIdx.x;
    if (i < NP) pc[i] = make_float2(beta[i], degree[i]);
}

// ---------------- ELL scatter (cnt must be zeroed) ----------------
__global__ void scatter_ell(const int* __restrict__ rows,
                            const int* __restrict__ cols,
                            const float* __restrict__ vals,
                            int* __restrict__ cnt,
                            int2* __restrict__ ev) {
    int e = blockIdx.x * 256 + threadIdx.x;
    if (e < NE) {
        int r = rows[e];
        int pos = atomicAdd(&cnt[r], 1);
        if (pos < CAP)
            ev[(size_t)r * CAP + pos] = make_int2(cols[e], __float_as_int(vals[e]));
    }
}

// ---------------- hop 1 fused: AH[r] = sum_e val * relu(W_in . x[col] + b_in) ----------------
// wave per row; edges preloaded one per lane (zero-padded past n); adaptive depth ladder
__global__ __launch_bounds__(256) void spmm_embed_kernel(
        const int* __restrict__ cnt, const int2* __restrict__ ev,
        const float2* __restrict__ pc,
        const float* __restrict__ W_in, const float* __restrict__ b_in,
        unsigned short* __restrict__ Y) {
    int w = threadIdx.x >> 6;
    int lane = threadIdx.x & 63;
    int r = blockIdx.x * 4 + w;
    if (r >= NP) return;
    int half = lane >> 5;
    int fo = (lane & 31) * 8;

    int n = min(cnt[r], CAP);
    int2 e2 = make_int2(0, 0);                 // val 0 beyond n -> padded steps harmless
    if (lane < n) e2 = ev[(size_t)r * CAP + lane];
    int col_l = e2.x;
    float val_l = __int_as_float(e2.y);

    float wr0[8], wr1[8], wr2[8], br[8];
    #pragma unroll
    for (int j = 0; j < 8; ++j) {
        wr0[j] = W_in[(fo + j) * 3 + 0];
        wr1[j] = W_in[(fo + j) * 3 + 1];
        wr2[j] = W_in[(fo + j) * 3 + 2];
        br[j]  = b_in[fo + j];
    }

    float acc[8] = {0.f,0.f,0.f,0.f,0.f,0.f,0.f,0.f};

#define ESTEP(d)                                                             \
    {                                                                        \
        float2 pr[d]; float vr[d];                                           \
        _Pragma("unroll")                                                    \
        for (int k = 0; k < (d); ++k) {                                      \
            int e = i + 2 * k + half;                                        \
            int c = __shfl(col_l, e);                                        \
            vr[k] = __shfl(val_l, e);                                        \
            pr[k] = pc[c];                                                   \
        }                                                                    \
        _Pragma("unroll")                                                    \
        for (int k = 0; k < (d); ++k) {                                      \
            float b = pr[k].x, dd = pr[k].y, v = vr[k];                      \
            float b2 = b * b;                                                \
            _Pragma("unroll")                                                \
            for (int j = 0; j < 8; ++j) {                                    \
                float t = fmaf(b, wr0[j], fmaf(b2, wr1[j], fmaf(dd, wr2[j], br[j]))); \
                acc[j] = fmaf(v, fmaxf(t, 0.f), acc[j]);                     \
            }                                                                \
        }                                                                    \
    }

    int i = 0;
    for (; i + 16 <= n; i += 16) ESTEP(8)
    if (i + 8 <= n) { ESTEP(4) i += 8; }
    if (i + 4 <= n) { ESTEP(2) i += 4; }
    if (i < n)      { ESTEP(2) }          // i % 4 == 0, i <= 60 -> shuffle lane <= 63
#undef ESTEP

    #pragma unroll
    for (int j = 0; j < 8; ++j) acc[j] += __shfl_xor(acc[j], 32);
    if (half == 0) {
        u16x8 o;
        #pragma unroll
        for (int j = 0; j < 8; ++j) o[j] = f2bf(acc[j]);
        *reinterpret_cast<u16x8*>(Y + (size_t)r * HIDDEN + fo) = o;
    }
}

// ---------------- hop 2: gather SpMM, adaptive depth ladder (max 8 gathers in flight) ----------------
__global__ __launch_bounds__(256) void spmm_gather_kernel(
        const int* __restrict__ cnt, const int2* __restrict__ ev,
        const unsigned short* __restrict__ X,
        unsigned short* __restrict__ Y) {
    int w = threadIdx.x >> 6;
    int lane = threadIdx.x & 63;
    int r = blockIdx.x * 4 + w;
    if (r >= NP) return;
    int half = lane >> 5;
    int fo = (lane & 31) * 8;

    int n = min(cnt[r], CAP);
    int2 e2 = make_int2(0, 0);
    if (lane < n) e2 = ev[(size_t)r * CAP + lane];
    int col_l = e2.x;
    float val_l = __int_as_float(e2.y);

    float acc[8] = {0.f,0.f,0.f,0.f,0.f,0.f,0.f,0.f};

#define GSTEP(d)                                                             \
    {                                                                        \
        u16x8 xr[d]; float vr[d];                                            \
        _Pragma("unroll")                                                    \
        for (int k = 0; k < (d); ++k) {                                      \
            int e = i + 2 * k + half;                                        \
            int c = __shfl(col_l, e);                                        \
            vr[k] = __shfl(val_l, e);                                        \
            xr[k] = *reinterpret_cast<const u16x8*>(X + (size_t)c * HIDDEN + fo); \
        }                                                                    \
        _Pragma("unroll")                                                    \
        for (int k = 0; k < (d); ++k)                                        \
            _Pragma("unroll")                                                \
            for (int j = 0; j < 8; ++j)                                      \
                acc[j] = fmaf(vr[k], bf2f(xr[k][j]), acc[j]);                \
    }

    int i = 0;
    for (; i + 16 <= n; i += 16) GSTEP(8)
    if (i + 8 <= n) { GSTEP(4) i += 8; }
    if (i + 4 <= n) { GSTEP(2) i += 4; }
    if (i < n)      { GSTEP(2) }
#undef GSTEP

    #pragma unroll
    for (int j = 0; j < 8; ++j) acc[j] += __shfl_xor(acc[j], 32);
    if (half == 0) {
        u16x8 o;
        #pragma unroll
        for (int j = 0; j < 8; ++j) o[j] = f2bf(acc[j]);
        *reinterpret_cast<u16x8*>(Y + (size_t)r * HIDDEN + fo) = o;
    }
}

// ---------------- fused MP GEMM (MFMA bf16) + relu + out-proj + softplus ----------------
// block: 512 threads = 8 waves; tile 128 rows x 256 cols; K = 512 in 8 chunks of 64
// K-chunks 0..3 read AH, 4..7 read A2H (both compact [P][256])
__global__ __launch_bounds__(512, 4) void mp_out_kernel(
        const unsigned short* __restrict__ AH,
        const unsigned short* __restrict__ A2H,
        const unsigned short* __restrict__ Bp,
        const float* __restrict__ W_out, const float* __restrict__ b_out,
        float* __restrict__ g) {
    __shared__ unsigned short As[128 * 64];    // 16 KB, XOR-swizzled
    __shared__ unsigned short Bs[8 * 256 * 8]; // 32 KB, [kbl][col][8]
    __shared__ float Ps[4][128];               // 2 KB partials

    int tid = threadIdx.x;
    int w = tid >> 6;
    int lane = tid & 63;
    int wr = w >> 2;
    int wc = w & 3;
    int p0 = blockIdx.x * 128;

    f32x4 acc[4][4];
    #pragma unroll
    for (int i = 0; i < 4; ++i)
        #pragma unroll
        for (int j = 0; j < 4; ++j)
            acc[i][j] = (f32x4){0.f, 0.f, 0.f, 0.f};

    for (int kc = 0; kc < 8; ++kc) {
        const unsigned short* Xsrc = (kc < 4) ? AH : A2H;
        int k0 = (kc & 3) * 64;
        __syncthreads();
        // stage A: 1024 x 16B slots. LDS[slot] = A_global[slot ^ swz(row)] (both-sides swizzle)
        #pragma unroll
        for (int it = 0; it < 2; ++it) {
            int slot = it * 512 + tid;
            int ss = slot ^ ((slot >> 3) & 7);         // involution, row bits untouched
            int row = ss >> 3;
            int ko = (ss & 7) * 8;
            int grow = p0 + row;
            if (grow >= NP) grow = NP - 1;
            float4 v = *reinterpret_cast<const float4*>(Xsrc + (size_t)grow * HIDDEN + k0 + ko);
            *reinterpret_cast<float4*>(&As[slot * 8]) = v;
        }
        // stage B: 2048 x 16B chunks, linear
        #pragma unroll
        for (int it = 0; it < 4; ++it) {
            int c2 = it * 512 + tid;
            float4 v = *reinterpret_cast<const float4*>(
                Bp + ((size_t)(kc * 8 + (c2 >> 8))) * 2048 + (c2 & 255) * 8);
            *reinterpret_cast<float4*>(&Bs[c2 * 8]) = v;
        }
        __syncthreads();
        #pragma unroll
        for (int ks = 0; ks < 2; ++ks) {
            bf16x8 af[4], bfr[4];
            #pragma unroll
            for (int rt = 0; rt < 4; ++rt) {
                int row = wr * 64 + rt * 16 + (lane & 15);
                int elem = row * 64 + ks * 32 + (lane >> 4) * 8;
                elem ^= (row & 7) << 3;                // matches staging swizzle
                af[rt] = *reinterpret_cast<const bf16x8*>(&As[elem]);
            }
            #pragma unroll
            for (int nt = 0; nt < 4; ++nt) {
                int col = wc * 64 + nt * 16 + (lane & 15);
                int kbl = ks * 4 + (lane >> 4);
                bfr[nt] = *reinterpret_cast<const bf16x8*>(&Bs[kbl * 2048 + col * 8]);
            }
            #pragma unroll
            for (int rt = 0; rt < 4; ++rt)
                #pragma unroll
                for (int nt = 0; nt < 4; ++nt)
                    acc[rt][nt] = __builtin_amdgcn_mfma_f32_16x16x32_bf16(
                        af[rt], bfr[nt], acc[rt][nt], 0, 0, 0);
        }
    }

    // epilogue: relu -> dot W_out (this wave's 64 cols) -> LDS partial
    float wv[4];
    #pragma unroll
    for (int nt = 0; nt < 4; ++nt)
        wv[nt] = W_out[wc * 64 + nt * 16 + (lane & 15)];

    float ps[4][4];
    #pragma unroll
    for (int rt = 0; rt < 4; ++rt)
        #pragma unroll
        for (int r = 0; r < 4; ++r) {
            float s = 0.f;
            #pragma unroll
            for (int nt = 0; nt < 4; ++nt)
                s = fmaf(fmaxf(acc[rt][nt][r], 0.0f), wv[nt], s);
            ps[rt][r] = s;
        }
    #pragma unroll
    for (int m = 1; m < 16; m <<= 1)
        #pragma unroll
        for (int rt = 0; rt < 4; ++rt)
            #pragma unroll
            for (int r = 0; r < 4; ++r)
                ps[rt][r] += __shfl_xor(ps[rt][r], m);

    if ((lane & 15) == 0) {
        int rb = wr * 64 + (lane >> 4) * 4;
        #pragma unroll
        for (int rt = 0; rt < 4; ++rt)
            #pragma unroll
            for (int r = 0; r < 4; ++r)
                Ps[wc][rb + rt * 16 + r] = ps[rt][r];
    }
    __syncthreads();
    if (tid < 128) {
        int p = p0 + tid;
        if (p < NP) {
            float z = Ps[0][tid] + Ps[1][tid] + Ps[2][tid] + Ps[3][tid] + b_out[0];
            g[p] = fmaxf(z, 0.0f) + log1pf(expf(-fabsf(z)));
        }
    }
}

extern "C" void kernel_launch(void* const* d_in, const int* in_sizes, int n_in,
                              void* d_out, int out_size, void* d_ws, size_t ws_size,
                              hipStream_t stream) {
    const float* beta   = (const float*)d_in[0];
    const float* degree = (const float*)d_in[1];
    const int*   A_rows = (const int*)d_in[2];
    const int*   A_cols = (const int*)d_in[3];
    const float* A_vals = (const float*)d_in[4];
    const float* W_in   = (const float*)d_in[5];
    const float* b_in   = (const float*)d_in[6];
    const float* W_mp1  = (const float*)d_in[7];
    const float* W_mp2  = (const float*)d_in[8];
    const float* W_out  = (const float*)d_in[9];
    const float* b_out  = (const float*)d_in[10];
    float* g = (float*)d_out;

    char* ws = (char*)d_ws;
    unsigned short* AH  = (unsigned short*)(ws + OFF_AH);
    unsigned short* A2H = (unsigned short*)(ws + OFF_A2H);
    unsigned short* Bp  = (unsigned short*)(ws + OFF_BP);
    int*    cnt = (int*)(ws + OFF_CNT);
    float2* pc  = (float2*)(ws + OFF_PC);
    int2*   ev  = (int2*)(ws + OFF_EV);

    hipMemsetAsync(cnt, 0, NP * sizeof(int), stream);

    bp_kernel<<<512, 256, 0, stream>>>(W_mp1, W_mp2, Bp);
    pc_kernel<<<(NP + 255) / 256, 256, 0, stream>>>(beta, degree, pc);

    scatter_ell<<<(NE + 255) / 256, 256, 0, stream>>>(A_rows, A_cols, A_vals, cnt, ev);

    // AH = A @ relu(x W_in^T + b_in)   (h recomputed per edge)
    spmm_embed_kernel<<<(NP + 3) / 4, 256, 0, stream>>>(cnt, ev, pc, W_in, b_in, AH);
    // A2H = A @ AH
    spmm_gather_kernel<<<(NP + 3) / 4, 256, 0, stream>>>(cnt, ev, AH, A2H);

    mp_out_kernel<<<(NP + 127) / 128, 512, 0, stream>>>(AH, A2H, Bp, W_out, b_out, g);
}